// Round 5
// baseline (219.763 us; speedup 1.0000x reference)
//
#include <hip/hip_runtime.h>
#include <hip/hip_bf16.h>
#include <math.h>

#define TB 16
#define LOG2E 1.44269504f

typedef float f32x4 __attribute__((ext_vector_type(4)));
typedef _Float16 f16x8 __attribute__((ext_vector_type(8)));
typedef _Float16 f16x4 __attribute__((ext_vector_type(4)));
typedef _Float16 f16x2 __attribute__((ext_vector_type(2)));

// ---------------- ws layout (bytes), all weight mats f16 [col][k] -----------
// W2TT @0      42*64*64 = 344064
// W1T  @344064 [64][64]   (k<40:W1[k][h], k==40:b1[h], else 0)
// WOA  @352256 [64][64]   WOE @360448
// VBA  @368640 [64][32]   (k<24 fused We@Wv, k==24 bias, else 0)   VBE @372736
// GA   @376832 [128][64]  G[col=h*32+k'][d] = 0.25*LOG2E * sum_dh Wq[d][h16+dh]*Kb[k'][h16+dh]
// GE   @393216 [128][64]
// GIH  @409600 [192][192] = gWih^T      GHH @483328 [192][64] = gWhh^T
// GBS  @507904 f32[192] (c<128: bih+bhh; else bih)    GBH @508672 f32[64]
// BHD  @508928 [32][64]  col<24 Ash, 24 a0, 25..30 Wm, 31 zero
#define OFF_W1T  344064
#define OFF_WOA  352256
#define OFF_WOE  360448
#define OFF_VBA  368640
#define OFF_VBE  372736
#define OFF_GA   376832
#define OFF_GE   393216
#define OFF_GIH  409600
#define OFF_GHH  483328
#define OFF_GBS  507904
#define OFF_GBH  508672
#define OFF_BHD  508928

#define MFH(a, b, c) __builtin_amdgcn_mfma_f32_16x16x32_f16((a), (b), (c), 0, 0, 0)

// ============================================================= prep =========
__global__ __launch_bounds__(256)
void prep_kernel(const float* __restrict__ hyp_W1, const float* __restrict__ hyp_b1,
                 const float* __restrict__ hyp_W2, const float* __restrict__ hyp_b2,
                 const float* __restrict__ Wa, const float* __restrict__ ba,
                 const float* __restrict__ We, const float* __restrict__ be,
                 const float* __restrict__ aWq, const float* __restrict__ aWk,
                 const float* __restrict__ aWv, const float* __restrict__ aWo,
                 const float* __restrict__ eWq, const float* __restrict__ eWk,
                 const float* __restrict__ eWv, const float* __restrict__ eWo,
                 const float* __restrict__ gWih, const float* __restrict__ gWhh,
                 const float* __restrict__ gbih, const float* __restrict__ gbhh,
                 const float* __restrict__ WzK, const float* __restrict__ WEK,
                 const float* __restrict__ Wm,
                 void* __restrict__ ws)
{
  const int b = blockIdx.x, t = threadIdx.x;
  if (b < 42) {
    _Float16* o = (_Float16*)ws;
    for (int i = t; i < 4096; i += 256) {
      int h = i >> 6, k = i & 63;
      float v;
      if (b < 40)       v = hyp_W2[(size_t)k * 2628 + b * 64 + h];
      else if (b == 40) v = hyp_W2[(size_t)k * 2628 + 2560 + h];
      else              v = (k < 40) ? hyp_b2[k * 64 + h]
                             : (k == 40 ? hyp_b2[2560 + h] : 0.0f);
      o[b * 4096 + i] = (_Float16)v;
    }
  } else if (b == 42) {
    _Float16* o = (_Float16*)((char*)ws + OFF_W1T);
    for (int i = t; i < 4096; i += 256) {
      int h = i >> 6, k = i & 63;
      float v = (k < 40) ? hyp_W1[k * 64 + h] : (k == 40 ? hyp_b1[h] : 0.0f);
      o[i] = (_Float16)v;
    }
  } else if (b == 43 || b == 44) {
    const float* M = (b == 43) ? aWo : eWo;
    _Float16* o = (_Float16*)((char*)ws + (b == 43 ? OFF_WOA : OFF_WOE));
    for (int i = t; i < 4096; i += 256)
      o[i] = (_Float16)M[(i & 63) * 64 + (i >> 6)];
  } else if (b == 45 || b == 46) {
    const float* Wemb = (b == 45) ? Wa : We;
    const float* bemb = (b == 45) ? ba : be;
    const float* Wv   = (b == 45) ? aWv : eWv;
    _Float16* o = (_Float16*)((char*)ws + (b == 45 ? OFF_VBA : OFF_VBE));
    for (int i = t; i < 2048; i += 256) {
      int h = i >> 5, k = i & 31;
      float v = 0.f;
      if (k < 24)       { for (int d = 0; d < 64; ++d) v += Wemb[k * 64 + d] * Wv[d * 64 + h]; }
      else if (k == 24) { for (int d = 0; d < 64; ++d) v += bemb[d] * Wv[d * 64 + h]; }
      o[i] = (_Float16)v;
    }
  } else if (b == 47 || b == 48) {
    const float* Wemb = (b == 47) ? Wa : We;
    const float* bemb = (b == 47) ? ba : be;
    const float* Wk   = (b == 47) ? aWk : eWk;
    const float* Wq   = (b == 47) ? aWq : eWq;
    _Float16* o = (_Float16*)((char*)ws + (b == 47 ? OFF_GA : OFF_GE));
    __shared__ float sKb[25 * 64];
    for (int i = t; i < 1600; i += 256) {
      int k = i >> 6, c = i & 63;
      float v = 0.f;
      if (k < 24)  { for (int d = 0; d < 64; ++d) v += Wemb[k * 64 + d] * Wk[d * 64 + c]; }
      else         { for (int d = 0; d < 64; ++d) v += bemb[d] * Wk[d * 64 + c]; }
      sKb[i] = v;
    }
    __syncthreads();
    for (int i = t; i < 8192; i += 256) {
      int col = i >> 6, d = i & 63;
      int h = col >> 5, kk = col & 31;
      float v = 0.f;
      if (kk < 25)
        for (int dh = 0; dh < 16; ++dh)
          v += Wq[d * 64 + h * 16 + dh] * sKb[kk * 64 + h * 16 + dh];
      o[i] = (_Float16)(v * 0.25f * LOG2E);
    }
  } else if (b == 49) {
    _Float16* o = (_Float16*)((char*)ws + OFF_GIH);
    for (int i = t; i < 36864; i += 256) {
      int d = i / 192, c = i - d * 192;
      o[c * 192 + d] = (_Float16)gWih[i];
    }
  } else if (b == 50) {
    _Float16* o = (_Float16*)((char*)ws + OFF_GHH);
    for (int i = t; i < 12288; i += 256) {
      int d = i / 192, c = i - d * 192;
      o[c * 64 + d] = (_Float16)gWhh[i];
    }
  } else if (b == 51) {
    float* gbS = (float*)((char*)ws + OFF_GBS);
    float* gbH = (float*)((char*)ws + OFF_GBH);
    if (t < 192) gbS[t] = gbih[t] + (t < 128 ? gbhh[t] : 0.0f);
    if (t < 64)  gbH[t] = gbhh[128 + t];
  } else { // b == 52 : head B-matrix
    __shared__ float sWsK[24 * 64];
    __shared__ float sbw[64];
    _Float16* o = (_Float16*)((char*)ws + OFF_BHD);
    for (int i = t; i < 1536; i += 256) {
      int j = i >> 6, h = i & 63;
      float v = 0.f;
      for (int c = 0; c < 64; ++c) v += We[j * 64 + c] * WEK[c * 64 + h];
      sWsK[i] = v;
    }
    if (t < 64) {
      float v = 0.f;
      for (int c = 0; c < 64; ++c) v += be[c] * WEK[c * 64 + t];
      sbw[t] = v;
    }
    __syncthreads();
    for (int i = t; i < 2048; i += 256) {
      int col = i >> 6, c = i & 63;
      float v = 0.f;
      if (col < 24)       { for (int d = 0; d < 64; ++d) v += WzK[c * 64 + d] * sWsK[col * 64 + d]; }
      else if (col == 24) { for (int d = 0; d < 64; ++d) v += WzK[c * 64 + d] * sbw[d]; }
      else if (col < 31)  v = Wm[c * 6 + (col - 25)];
      o[i] = (_Float16)v;
    }
  }
}

// ============================================================= main =========
__global__ __launch_bounds__(256, 6)
void agent_kernel(
    const float* __restrict__ own_raw, const float* __restrict__ ally_raw,
    const float* __restrict__ enemy_raw, const float* __restrict__ hidden,
    const float* __restrict__ bm,
    const void* __restrict__ ws,
    float* __restrict__ out, int BN)
{
  __shared__ _Float16 s_u16[TB * 200];       // own_e | zA | zE (cols 0..191)
  __shared__ _Float16 s_hid16[TB * 72];
  __shared__ __align__(16) char s_pool[18432];

  const int tid = threadIdx.x;
  const int bs0 = blockIdx.x * TB;
  const int s   = tid >> 4;
  const int ln  = tid & 15;
  const int l   = tid & 63;
  const int wv  = tid >> 6;
  const int lr  = l & 15;
  const int oct = l >> 4;

  float*     s_w     = (float*)s_pool;                   // [16][132] f32
  _Float16*  s_p16   = (_Float16*)(s_pool + 8448);       // [16n][72]: p(n,s,h)=n*72+s*4+h
  _Float16*  s_rawh  = (_Float16*)(s_pool + 10752);      // [6][16][40] f16
  _Float16*  s_att16 = (_Float16*)s_pool;                // [16][72]  (w dead)
  _Float16*  s_own16 = (_Float16*)s_pool;                // [16][56]  (ph0-2)
  _Float16*  s_h116  = (_Float16*)(s_pool + 1792);       // [16][72]  (ph1-2)
  _Float16*  s_z16   = (_Float16*)s_pool;                // [16][72]  (ph4-5)
  float*     s_t     = (float*)(s_pool + 2304);          // [16][26]  (ph5)

  const f16x8 ZERO8F = {0,0,0,0,0,0,0,0};
  f16x8 ONE8F = ZERO8F; ONE8F[0] = (_Float16)1.0f;
  const f32x4 ZERO4 = {0.f, 0.f, 0.f, 0.f};

  // ---------------- phase 0: stage own + hidden (f16) ----------------
  for (int i = tid; i < 320; i += 256) {           // 16*40 f32 as float2
    int ss = i / 20, c = i - ss * 20;
    float2 v = *(const float2*)(own_raw + (size_t)(bs0 + ss) * 40 + c * 2);
    f16x2 pk; pk[0] = (_Float16)v.x; pk[1] = (_Float16)v.y;
    *(f16x2*)(s_own16 + ss * 56 + c * 2) = pk;
  }
  for (int i = tid; i < 512; i += 256) {           // 16*64 f32
    int ss = i >> 5, c = i & 31;
    float2 v = *(const float2*)(hidden + (size_t)(bs0 + ss) * 64 + c * 2);
    f16x2 pk; pk[0] = (_Float16)v.x; pk[1] = (_Float16)v.y;
    *(f16x2*)(s_hid16 + ss * 72 + c * 2) = pk;
  }
  __syncthreads();

  // ---------------- phase 1: h1 = relu(own @ W1 + b1) ----------------
  {
    const _Float16* w1t = (const _Float16*)((const char*)ws + OFF_W1T);
    f16x8 a0 = *(const f16x8*)(s_own16 + lr * 56 + oct * 8);
    f16x8 a1;
    if (oct == 0)      a1 = *(const f16x8*)(s_own16 + lr * 56 + 32);
    else if (oct == 1) a1 = ONE8F;
    else               a1 = ZERO8F;
    f16x8 b0 = *(const f16x8*)(w1t + (wv * 16 + lr) * 64 + oct * 8);
    f16x8 b1 = *(const f16x8*)(w1t + (wv * 16 + lr) * 64 + 32 + oct * 8);
    f32x4 acc = ZERO4;
    acc = MFH(a0, b0, acc);
    acc = MFH(a1, b1, acc);
    #pragma unroll
    for (int j = 0; j < 4; ++j)
      s_h116[(oct * 4 + j) * 72 + wv * 16 + lr] = (_Float16)fmaxf(acc[j], 0.f);
  }
  __syncthreads();

  // ---------------- phase 2: own_e = P @ W2T (f16 MFMA, dual acc) ----------
  {
    const _Float16* bb = (const _Float16*)ws + (size_t)(wv * 16 + lr) * 64 + oct * 8;
    f16x8 h0f = *(const f16x8*)(s_h116 + lr * 72 + oct * 8);
    f16x8 h1f = *(const f16x8*)(s_h116 + lr * 72 + 32 + oct * 8);
    f32x4 accA = ZERO4, accB = ZERO4;
    #pragma unroll 4
    for (int f = 0; f < 40; ++f) {
      f16x8 b0 = *(const f16x8*)(bb + (size_t)f * 4096);
      f16x8 b1 = *(const f16x8*)(bb + (size_t)f * 4096 + 32);
      _Float16 ov = s_own16[lr * 56 + f];
      f16x8 a0, a1;
      #pragma unroll
      for (int k = 0; k < 8; ++k) { a0[k] = h0f[k] * ov; a1[k] = h1f[k] * ov; }
      if (f & 1) { accB = MFH(a0, b0, accB); accB = MFH(a1, b1, accB); }
      else       { accA = MFH(a0, b0, accA); accA = MFH(a1, b1, accA); }
    }
    { // f=40: h1 tile
      f16x8 b0 = *(const f16x8*)(bb + (size_t)40 * 4096);
      f16x8 b1 = *(const f16x8*)(bb + (size_t)40 * 4096 + 32);
      accA = MFH(h0f, b0, accA);
      accA = MFH(h1f, b1, accA);
    }
    { // f=41: [own | 1 | 0] bias tile
      f16x8 b0 = *(const f16x8*)(bb + (size_t)41 * 4096);
      f16x8 b1 = *(const f16x8*)(bb + (size_t)41 * 4096 + 32);
      f16x8 a0 = *(const f16x8*)(s_own16 + lr * 56 + oct * 8);
      f16x8 a1;
      if (oct == 0)      a1 = *(const f16x8*)(s_own16 + lr * 56 + 32);
      else if (oct == 1) a1 = ONE8F;
      else               a1 = ZERO8F;
      accB = MFH(a0, b0, accB);
      accB = MFH(a1, b1, accB);
    }
    #pragma unroll
    for (int j = 0; j < 4; ++j)
      s_u16[(oct * 4 + j) * 200 + wv * 16 + lr] = (_Float16)(accA[j] + accB[j]);
  }
  __syncthreads();

  // ---------------- phase 3: MHA via G-trick ----------------
  for (int side = 0; side < 2; ++side) {
    const int n_ent = side ? 16 : 15;
    const int rstr  = side ? 384 : 360;
    const float* rawg = side ? enemy_raw : ally_raw;
    const _Float16* woT = (const _Float16*)((const char*)ws + (side ? OFF_WOE : OFF_WOA));
    const _Float16* vbT = (const _Float16*)((const char*)ws + (side ? OFF_VBE : OFF_VBA));
    const _Float16* gT  = (const _Float16*)((const char*)ws + (side ? OFF_GE  : OFF_GA));

    // --- w = own_e @ G -> s_w[16][132]; stage raw batch 0 ---
    {
      f16x8 a0 = *(const f16x8*)(s_u16 + lr * 200 + oct * 8);
      f16x8 a1 = *(const f16x8*)(s_u16 + lr * 200 + 32 + oct * 8);
      #pragma unroll
      for (int t2 = 0; t2 < 2; ++t2) {
        int col = wv * 32 + t2 * 16 + lr;
        f16x8 b0 = *(const f16x8*)(gT + col * 64 + oct * 8);
        f16x8 b1 = *(const f16x8*)(gT + col * 64 + 32 + oct * 8);
        f32x4 acc = ZERO4;
        acc = MFH(a0, b0, acc);
        acc = MFH(a1, b1, acc);
        #pragma unroll
        for (int j = 0; j < 4; ++j)
          s_w[(oct * 4 + j) * 132 + col] = acc[j];
      }
      int c2 = n_ent < 6 ? n_ent : 6;
      for (int i = tid; i < c2 * 192; i += 256) {
        int nn = i / 192, r = i - nn * 192, s2 = r / 12, cc = r - s2 * 12;
        float2 v = *(const float2*)(rawg + (size_t)(bs0 + s2) * rstr + nn * 24 + cc * 2);
        f16x2 pk; pk[0] = (_Float16)v.x; pk[1] = (_Float16)v.y;
        *(f16x2*)(s_rawh + nn * 640 + s2 * 40 + cc * 2) = pk;
      }
    }
    __syncthreads();

    // --- score: thread (s, n); 4 head scores; 16-lane softmax ---
    {
      float sc0, sc1, sc2, sc3;
      if (ln < n_ent) {
        const float* rp = rawg + (size_t)(bs0 + s) * rstr + ln * 24;
        const float* wp = s_w + s * 132;
        sc0 = wp[24]; sc1 = wp[56]; sc2 = wp[88]; sc3 = wp[120];
        bool msk = false;
        #pragma unroll
        for (int k4 = 0; k4 < 6; ++k4) {
          float4 r4 = *(const float4*)(rp + k4 * 4);
          msk = msk || r4.x != 0.f || r4.y != 0.f || r4.z != 0.f || r4.w != 0.f;
          float4 w0 = *(const float4*)(wp + k4 * 4);
          float4 w1 = *(const float4*)(wp + 32 + k4 * 4);
          float4 w2 = *(const float4*)(wp + 64 + k4 * 4);
          float4 w3 = *(const float4*)(wp + 96 + k4 * 4);
          sc0 += r4.x*w0.x + r4.y*w0.y + r4.z*w0.z + r4.w*w0.w;
          sc1 += r4.x*w1.x + r4.y*w1.y + r4.z*w1.z + r4.w*w1.w;
          sc2 += r4.x*w2.x + r4.y*w2.y + r4.z*w2.z + r4.w*w2.w;
          sc3 += r4.x*w3.x + r4.y*w3.y + r4.z*w3.z + r4.w*w3.w;
        }
        if (!msk) { sc0 = sc1 = sc2 = sc3 = -1.0e9f; }
      } else {
        sc0 = sc1 = sc2 = sc3 = -2.0e9f;   // phantom entity (ally n=15)
      }
      float m0 = sc0, m1 = sc1, m2 = sc2, m3 = sc3;
      #pragma unroll
      for (int d = 1; d < 16; d <<= 1) {
        m0 = fmaxf(m0, __shfl_xor(m0, d));
        m1 = fmaxf(m1, __shfl_xor(m1, d));
        m2 = fmaxf(m2, __shfl_xor(m2, d));
        m3 = fmaxf(m3, __shfl_xor(m3, d));
      }
      float p0 = __builtin_exp2f(sc0 - m0);
      float p1 = __builtin_exp2f(sc1 - m1);
      float p2 = __builtin_exp2f(sc2 - m2);
      float p3 = __builtin_exp2f(sc3 - m3);
      float l0 = p0, l1 = p1, l2 = p2, l3 = p3;
      #pragma unroll
      for (int d = 1; d < 16; d <<= 1) {
        l0 += __shfl_xor(l0, d);
        l1 += __shfl_xor(l1, d);
        l2 += __shfl_xor(l2, d);
        l3 += __shfl_xor(l3, d);
      }
      f16x4 pk;
      pk[0] = (_Float16)(p0 * __builtin_amdgcn_rcpf(l0));
      pk[1] = (_Float16)(p1 * __builtin_amdgcn_rcpf(l1));
      pk[2] = (_Float16)(p2 * __builtin_amdgcn_rcpf(l2));
      pk[3] = (_Float16)(p3 * __builtin_amdgcn_rcpf(l3));
      *(f16x4*)(s_p16 + ln * 72 + s * 4) = pk;
    }
    __syncthreads();

    // --- PV: o += p_n * (rawext_n @ Vb), p folded into A-frag ---
    f16x8 vbF = *(const f16x8*)(vbT + (wv * 16 + lr) * 32 + oct * 8);
    f32x4 oaccA = ZERO4, oaccB = ZERO4;
    int done = 0;
    while (done < n_ent) {
      int cnt = n_ent - done < 6 ? n_ent - done : 6;
      for (int i = 0; i < cnt; ++i) {
        _Float16 pv = s_p16[(done + i) * 72 + lr * 4 + wv];
        f16x8 frag;
        if (oct < 3) {
          f16x8 rv = *(const f16x8*)(s_rawh + i * 640 + lr * 40 + oct * 8);
          #pragma unroll
          for (int k = 0; k < 8; ++k) frag[k] = rv[k] * pv;
        } else {
          frag = ZERO8F; frag[0] = pv;     // bias row k=24
        }
        if (i & 1) oaccB = MFH(frag, vbF, oaccB);
        else       oaccA = MFH(frag, vbF, oaccA);
      }
      done += cnt;
      __syncthreads();
      if (done < n_ent) {
        int c2 = n_ent - done < 6 ? n_ent - done : 6;
        for (int i = tid; i < c2 * 192; i += 256) {
          int nn = i / 192, r = i - nn * 192, s2 = r / 12, cc = r - s2 * 12;
          float2 v = *(const float2*)(rawg + (size_t)(bs0 + s2) * rstr + (done + nn) * 24 + cc * 2);
          f16x2 pk; pk[0] = (_Float16)v.x; pk[1] = (_Float16)v.y;
          *(f16x2*)(s_rawh + nn * 640 + s2 * 40 + cc * 2) = pk;
        }
        __syncthreads();
      }
    }
    #pragma unroll
    for (int j = 0; j < 4; ++j)
      s_att16[(oct * 4 + j) * 72 + wv * 16 + lr] = (_Float16)(oaccA[j] + oaccB[j]);
    __syncthreads();

    // --- o-GEMM -> u[:, 64 + side*64] ---
    {
      f16x8 a0 = *(const f16x8*)(s_att16 + lr * 72 + oct * 8);
      f16x8 a1 = *(const f16x8*)(s_att16 + lr * 72 + 32 + oct * 8);
      f16x8 b0 = *(const f16x8*)(woT + (wv * 16 + lr) * 64 + oct * 8);
      f16x8 b1 = *(const f16x8*)(woT + (wv * 16 + lr) * 64 + 32 + oct * 8);
      f32x4 oa = ZERO4;
      oa = MFH(a0, b0, oa);
      oa = MFH(a1, b1, oa);
      #pragma unroll
      for (int j = 0; j < 4; ++j)
        s_u16[(oct * 4 + j) * 200 + 64 + side * 64 + wv * 16 + lr] = (_Float16)oa[j];
    }
    __syncthreads();
  }

  // ---------------- phase 4: GRU (f16 MFMA, in-register pointwise) ---------
  {
    const _Float16* ihT = (const _Float16*)((const char*)ws + OFF_GIH);
    const _Float16* hhT = (const _Float16*)((const char*)ws + OFF_GHH);
    const float* gbS = (const float*)((const char*)ws + OFF_GBS);
    const float* gbH = (const float*)((const char*)ws + OFF_GBH);
    f32x4 aX0 = ZERO4, aX1 = ZERO4, aX2 = ZERO4, aH2 = ZERO4;
    #pragma unroll
    for (int st = 0; st < 6; ++st) {
      f16x8 uf = *(const f16x8*)(s_u16 + lr * 200 + st * 32 + oct * 8);
      f16x8 b0 = *(const f16x8*)(ihT + ((wv    ) * 16 + lr) * 192 + st * 32 + oct * 8);
      f16x8 b1 = *(const f16x8*)(ihT + ((wv + 4) * 16 + lr) * 192 + st * 32 + oct * 8);
      f16x8 b2 = *(const f16x8*)(ihT + ((wv + 8) * 16 + lr) * 192 + st * 32 + oct * 8);
      aX0 = MFH(uf, b0, aX0);
      aX1 = MFH(uf, b1, aX1);
      aX2 = MFH(uf, b2, aX2);
    }
    #pragma unroll
    for (int st = 0; st < 2; ++st) {
      f16x8 hf = *(const f16x8*)(s_hid16 + lr * 72 + st * 32 + oct * 8);
      f16x8 b0 = *(const f16x8*)(hhT + ((wv    ) * 16 + lr) * 64 + st * 32 + oct * 8);
      f16x8 b1 = *(const f16x8*)(hhT + ((wv + 4) * 16 + lr) * 64 + st * 32 + oct * 8);
      f16x8 b2 = *(const f16x8*)(hhT + ((wv + 8) * 16 + lr) * 64 + st * 32 + oct * 8);
      aX0 = MFH(hf, b0, aX0);
      aX1 = MFH(hf, b1, aX1);
      aH2 = MFH(hf, b2, aH2);
    }
    const int c0 = wv * 16 + lr;
    float bb0 = gbS[c0], bb1 = gbS[c0 + 64], bb2 = gbS[c0 + 128], bbh = gbH[c0];
    #pragma unroll
    for (int j = 0; j < 4; ++j) {
      int row = oct * 4 + j;
      float xr = aX0[j] + bb0;
      float xz = aX1[j] + bb1;
      float xn = aX2[j] + bb2;
      float hn = aH2[j] + bbh;
      float r  = __builtin_amdgcn_rcpf(1.f + __builtin_exp2f(-xr * LOG2E));
      float zg = __builtin_amdgcn_rcpf(1.f + __builtin_exp2f(-xz * LOG2E));
      float ta = xn + r * hn;
      float nc = 1.f - 2.f * __builtin_amdgcn_rcpf(1.f + __builtin_exp2f(2.f * LOG2E * ta));
      float hv = (float)s_hid16[row * 72 + c0];
      float zz = (1.f - zg) * nc + zg * hv;
      s_z16[row * 72 + c0] = (_Float16)zz;
      out[(size_t)BN * 22 + (size_t)(bs0 + row) * 64 + c0] = zz;
    }
  }
  __syncthreads();

  // ---------------- phase 5: fused head GEMM + shoot logits ----------------
  {
    const _Float16* bhT = (const _Float16*)((const char*)ws + OFF_BHD);
    if (wv < 2) {
      f16x8 a0 = *(const f16x8*)(s_z16 + lr * 72 + oct * 8);
      f16x8 a1 = *(const f16x8*)(s_z16 + lr * 72 + 32 + oct * 8);
      f16x8 b0 = *(const f16x8*)(bhT + (wv * 16 + lr) * 64 + oct * 8);
      f16x8 b1 = *(const f16x8*)(bhT + (wv * 16 + lr) * 64 + 32 + oct * 8);
      f32x4 td = ZERO4;
      td = MFH(a0, b0, td);
      td = MFH(a1, b1, td);
      const int col = wv * 16 + lr;
      #pragma unroll
      for (int j = 0; j < 4; ++j) {
        int row = oct * 4 + j;
        if (col < 25)      s_t[row * 26 + col] = td[j];
        else if (col < 31) out[(size_t)(bs0 + row) * 22 + (col - 25)] = td[j] + bm[col - 25];
      }
    }
  }
  __syncthreads();
  {
    const float* er = enemy_raw + (size_t)(bs0 + s) * 384 + ln * 24;
    const float* tp = s_t + s * 26;
    float acc2 = tp[24];
    #pragma unroll
    for (int k4 = 0; k4 < 6; ++k4) {
      float4 r4 = *(const float4*)(er + k4 * 4);
      acc2 += r4.x * tp[k4*4] + r4.y * tp[k4*4+1] + r4.z * tp[k4*4+2] + r4.w * tp[k4*4+3];
    }
    out[(size_t)(bs0 + s) * 22 + 6 + ln] = acc2;
  }
}

// ============================================================= launch =======
extern "C" void kernel_launch(void* const* d_in, const int* in_sizes, int n_in,
                              void* d_out, int out_size, void* d_ws, size_t ws_size,
                              hipStream_t stream) {
  (void)n_in; (void)out_size; (void)ws_size;
  const float* own_raw   = (const float*)d_in[0];
  const float* ally_raw  = (const float*)d_in[1];
  const float* enemy_raw = (const float*)d_in[2];
  const float* hidden    = (const float*)d_in[3];
  const float* hyp_W1    = (const float*)d_in[4];
  const float* hyp_b1    = (const float*)d_in[5];
  const float* hyp_W2    = (const float*)d_in[6];
  const float* hyp_b2    = (const float*)d_in[7];
  const float* Wa        = (const float*)d_in[8];
  const float* ba        = (const float*)d_in[9];
  const float* We        = (const float*)d_in[10];
  const float* be        = (const float*)d_in[11];
  const float* aWq       = (const float*)d_in[12];
  const float* aWk       = (const float*)d_in[13];
  const float* aWv       = (const float*)d_in[14];
  const float* aWo       = (const float*)d_in[15];
  const float* eWq       = (const float*)d_in[16];
  const float* eWk       = (const float*)d_in[17];
  const float* eWv       = (const float*)d_in[18];
  const float* eWo       = (const float*)d_in[19];
  const float* gWih      = (const float*)d_in[20];
  const float* gWhh      = (const float*)d_in[21];
  const float* gbih      = (const float*)d_in[22];
  const float* gbhh      = (const float*)d_in[23];
  const float* Wm        = (const float*)d_in[24];
  const float* bm        = (const float*)d_in[25];
  const float* WzK       = (const float*)d_in[26];
  const float* WEK       = (const float*)d_in[27];
  int BN = in_sizes[0] / 40;
  int blocks = BN / TB;

  hipLaunchKernelGGL(prep_kernel, dim3(53), dim3(256), 0, stream,
                     hyp_W1, hyp_b1, hyp_W2, hyp_b2, Wa, ba, We, be,
                     aWq, aWk, aWv, aWo, eWq, eWk, eWv, eWo,
                     gWih, gWhh, gbih, gbhh, WzK, WEK, Wm, d_ws);
  hipLaunchKernelGGL(agent_kernel, dim3(blocks), dim3(256), 0, stream,
                     own_raw, ally_raw, enemy_raw, hidden, bm,
                     d_ws, (float*)d_out, BN);
}

// Round 6
// 193.659 us; speedup vs baseline: 1.1348x; 1.1348x over previous
//
#include <hip/hip_runtime.h>
#include <hip/hip_bf16.h>
#include <math.h>

#define TB 16
#define LOG2E 1.44269504f

typedef float f32x4 __attribute__((ext_vector_type(4)));
typedef _Float16 f16x8 __attribute__((ext_vector_type(8)));
typedef _Float16 f16x4 __attribute__((ext_vector_type(4)));
typedef _Float16 f16x2 __attribute__((ext_vector_type(2)));
typedef unsigned int u32x4 __attribute__((ext_vector_type(4)));

// ---------------- ws layout (bytes), all weight mats f16 [col][k] -----------
#define OFF_W1T  344064
#define OFF_WOA  352256
#define OFF_WOE  360448
#define OFF_VBA  368640
#define OFF_VBE  372736
#define OFF_GA   376832
#define OFF_GE   393216
#define OFF_GIH  409600
#define OFF_GHH  483328
#define OFF_GBS  507904
#define OFF_GBH  508672
#define OFF_BHD  508928

#define MFH(a, b, c) __builtin_amdgcn_mfma_f32_16x16x32_f16((a), (b), (c), 0, 0, 0)

// ============================================================= prep =========
__global__ __launch_bounds__(256)
void prep_kernel(const float* __restrict__ hyp_W1, const float* __restrict__ hyp_b1,
                 const float* __restrict__ hyp_W2, const float* __restrict__ hyp_b2,
                 const float* __restrict__ Wa, const float* __restrict__ ba,
                 const float* __restrict__ We, const float* __restrict__ be,
                 const float* __restrict__ aWq, const float* __restrict__ aWk,
                 const float* __restrict__ aWv, const float* __restrict__ aWo,
                 const float* __restrict__ eWq, const float* __restrict__ eWk,
                 const float* __restrict__ eWv, const float* __restrict__ eWo,
                 const float* __restrict__ gWih, const float* __restrict__ gWhh,
                 const float* __restrict__ gbih, const float* __restrict__ gbhh,
                 const float* __restrict__ WzK, const float* __restrict__ WEK,
                 const float* __restrict__ Wm,
                 void* __restrict__ ws)
{
  const int b = blockIdx.x, t = threadIdx.x;
  if (b < 42) {
    _Float16* o = (_Float16*)ws;
    for (int i = t; i < 4096; i += 256) {
      int h = i >> 6, k = i & 63;
      float v;
      if (b < 40)       v = hyp_W2[(size_t)k * 2628 + b * 64 + h];
      else if (b == 40) v = hyp_W2[(size_t)k * 2628 + 2560 + h];
      else              v = (k < 40) ? hyp_b2[k * 64 + h]
                             : (k == 40 ? hyp_b2[2560 + h] : 0.0f);
      o[b * 4096 + i] = (_Float16)v;
    }
  } else if (b == 42) {
    _Float16* o = (_Float16*)((char*)ws + OFF_W1T);
    for (int i = t; i < 4096; i += 256) {
      int h = i >> 6, k = i & 63;
      float v = (k < 40) ? hyp_W1[k * 64 + h] : (k == 40 ? hyp_b1[h] : 0.0f);
      o[i] = (_Float16)v;
    }
  } else if (b == 43 || b == 44) {
    const float* M = (b == 43) ? aWo : eWo;
    _Float16* o = (_Float16*)((char*)ws + (b == 43 ? OFF_WOA : OFF_WOE));
    for (int i = t; i < 4096; i += 256)
      o[i] = (_Float16)M[(i & 63) * 64 + (i >> 6)];
  } else if (b == 45 || b == 46) {
    const float* Wemb = (b == 45) ? Wa : We;
    const float* bemb = (b == 45) ? ba : be;
    const float* Wv   = (b == 45) ? aWv : eWv;
    _Float16* o = (_Float16*)((char*)ws + (b == 45 ? OFF_VBA : OFF_VBE));
    for (int i = t; i < 2048; i += 256) {
      int h = i >> 5, k = i & 31;
      float v = 0.f;
      if (k < 24)       { for (int d = 0; d < 64; ++d) v += Wemb[k * 64 + d] * Wv[d * 64 + h]; }
      else if (k == 24) { for (int d = 0; d < 64; ++d) v += bemb[d] * Wv[d * 64 + h]; }
      o[i] = (_Float16)v;
    }
  } else if (b == 47 || b == 48) {
    const float* Wemb = (b == 47) ? Wa : We;
    const float* bemb = (b == 47) ? ba : be;
    const float* Wk   = (b == 47) ? aWk : eWk;
    const float* Wq   = (b == 47) ? aWq : eWq;
    _Float16* o = (_Float16*)((char*)ws + (b == 47 ? OFF_GA : OFF_GE));
    __shared__ float sKb[25 * 64];
    for (int i = t; i < 1600; i += 256) {
      int k = i >> 6, c = i & 63;
      float v = 0.f;
      if (k < 24)  { for (int d = 0; d < 64; ++d) v += Wemb[k * 64 + d] * Wk[d * 64 + c]; }
      else         { for (int d = 0; d < 64; ++d) v += bemb[d] * Wk[d * 64 + c]; }
      sKb[i] = v;
    }
    __syncthreads();
    for (int i = t; i < 8192; i += 256) {
      int col = i >> 6, d = i & 63;
      int h = col >> 5, kk = col & 31;
      float v = 0.f;
      if (kk < 25)
        for (int dh = 0; dh < 16; ++dh)
          v += Wq[d * 64 + h * 16 + dh] * sKb[kk * 64 + h * 16 + dh];
      o[i] = (_Float16)(v * 0.25f * LOG2E);
    }
  } else if (b == 49) {
    _Float16* o = (_Float16*)((char*)ws + OFF_GIH);
    for (int i = t; i < 36864; i += 256) {
      int d = i / 192, c = i - d * 192;
      o[c * 192 + d] = (_Float16)gWih[i];
    }
  } else if (b == 50) {
    _Float16* o = (_Float16*)((char*)ws + OFF_GHH);
    for (int i = t; i < 12288; i += 256) {
      int d = i / 192, c = i - d * 192;
      o[c * 64 + d] = (_Float16)gWhh[i];
    }
  } else if (b == 51) {
    float* gbS = (float*)((char*)ws + OFF_GBS);
    float* gbH = (float*)((char*)ws + OFF_GBH);
    if (t < 192) gbS[t] = gbih[t] + (t < 128 ? gbhh[t] : 0.0f);
    if (t < 64)  gbH[t] = gbhh[128 + t];
  } else { // b == 52 : head B-matrix
    __shared__ float sWsK[24 * 64];
    __shared__ float sbw[64];
    _Float16* o = (_Float16*)((char*)ws + OFF_BHD);
    for (int i = t; i < 1536; i += 256) {
      int j = i >> 6, h = i & 63;
      float v = 0.f;
      for (int c = 0; c < 64; ++c) v += We[j * 64 + c] * WEK[c * 64 + h];
      sWsK[i] = v;
    }
    if (t < 64) {
      float v = 0.f;
      for (int c = 0; c < 64; ++c) v += be[c] * WEK[c * 64 + t];
      sbw[t] = v;
    }
    __syncthreads();
    for (int i = t; i < 2048; i += 256) {
      int col = i >> 6, c = i & 63;
      float v = 0.f;
      if (col < 24)       { for (int d = 0; d < 64; ++d) v += WzK[c * 64 + d] * sWsK[col * 64 + d]; }
      else if (col == 24) { for (int d = 0; d < 64; ++d) v += WzK[c * 64 + d] * sbw[d]; }
      else if (col < 31)  v = Wm[c * 6 + (col - 25)];
      o[i] = (_Float16)v;
    }
  }
}

// ============================================================= main =========
__global__ __launch_bounds__(256, 5)
void agent_kernel(
    const float* __restrict__ own_raw, const float* __restrict__ ally_raw,
    const float* __restrict__ enemy_raw, const float* __restrict__ hidden,
    const float* __restrict__ bm,
    const void* __restrict__ ws,
    float* __restrict__ out, int BN)
{
  __shared__ _Float16 s_u16[TB * 196];       // own_e | zA | zE
  __shared__ _Float16 s_hid16[TB * 68];
  __shared__ __align__(16) char s_pool[23936];
  // 0..17408      s_rawh [16n][16s][34] f16, 16B-chunk XOR-swizzled by (n&3)
  // 17408..21632  ph0-2: own16(1792)+h116@19200(2304) | ph3: w16 [16][132] f16
  //               post-PV: att16 [16][72] | ph4+: z16 [16][72] + s_t@19712 [16][26] f32
  // 21632..23936  p16 [16n][s*4+h pad 72] f16 | ph5: s_q [16][22] f32

  const int tid = threadIdx.x;
  const int bs0 = blockIdx.x * TB;
  const int s   = tid >> 4;
  const int ln  = tid & 15;
  const int l   = tid & 63;
  const int wv  = tid >> 6;
  const int lr  = l & 15;
  const int oct = l >> 4;

  _Float16* s_own16 = (_Float16*)(s_pool + 17408);
  _Float16* s_h116  = (_Float16*)(s_pool + 19200);
  _Float16* s_w16   = (_Float16*)(s_pool + 17408);
  _Float16* s_att16 = (_Float16*)(s_pool + 17408);
  _Float16* s_z16   = (_Float16*)(s_pool + 17408);
  float*    s_t     = (float*)(s_pool + 19712);
  _Float16* s_p16   = (_Float16*)(s_pool + 21632);
  float*    s_q     = (float*)(s_pool + 21632);

  const f16x8 ZERO8F = {0,0,0,0,0,0,0,0};
  f16x8 ONE8F = ZERO8F; ONE8F[0] = (_Float16)1.0f;
  const f32x4 ZERO4 = {0.f, 0.f, 0.f, 0.f};

  // ---------------- phase 0: stage own + hidden + ALLY raw ----------------
  for (int i = tid; i < 320; i += 256) {
    int ss = i / 20, c = i - ss * 20;
    float2 v = *(const float2*)(own_raw + (size_t)(bs0 + ss) * 40 + c * 2);
    f16x2 pk; pk[0] = (_Float16)v.x; pk[1] = (_Float16)v.y;
    *(f16x2*)(s_own16 + ss * 56 + c * 2) = pk;
  }
  for (int i = tid; i < 512; i += 256) {
    int ss = i >> 5, c = i & 31;
    float2 v = *(const float2*)(hidden + (size_t)(bs0 + ss) * 64 + c * 2);
    f16x2 pk; pk[0] = (_Float16)v.x; pk[1] = (_Float16)v.y;
    *(f16x2*)(s_hid16 + ss * 68 + c * 2) = pk;
  }
  for (int i = tid; i < 2880; i += 256) {   // 15 ents * 16 s * 12 float2
    int nn = i / 192, r = i - nn * 192, s2 = r / 12, cc = r - s2 * 12;
    float2 v = *(const float2*)(ally_raw + (size_t)(bs0 + s2) * 360 + nn * 24 + cc * 2);
    f16x2 pk; pk[0] = (_Float16)v.x; pk[1] = (_Float16)v.y;
    int byte = cc * 4;
    int sw = ((((byte >> 4) ^ (nn & 3)) << 4) | (byte & 15));
    *(f16x2*)(s_pool + nn * 1088 + s2 * 68 + sw) = pk;
  }
  __syncthreads();

  // ---------------- phase 1: h1 = relu(own @ W1 + b1) ----------------
  {
    const _Float16* w1t = (const _Float16*)((const char*)ws + OFF_W1T);
    f16x8 a0 = *(const f16x8*)(s_own16 + lr * 56 + oct * 8);
    f16x8 a1;
    if (oct == 0)      a1 = *(const f16x8*)(s_own16 + lr * 56 + 32);
    else if (oct == 1) a1 = ONE8F;
    else               a1 = ZERO8F;
    f16x8 b0 = *(const f16x8*)(w1t + (wv * 16 + lr) * 64 + oct * 8);
    f16x8 b1 = *(const f16x8*)(w1t + (wv * 16 + lr) * 64 + 32 + oct * 8);
    f32x4 acc = ZERO4;
    acc = MFH(a0, b0, acc);
    acc = MFH(a1, b1, acc);
    #pragma unroll
    for (int j = 0; j < 4; ++j)
      s_h116[(oct * 4 + j) * 72 + wv * 16 + lr] = (_Float16)fmaxf(acc[j], 0.f);
  }
  __syncthreads();

  // ---------------- phase 2: own_e = P @ W2T (f16 MFMA, dual acc) ----------
  {
    const _Float16* bb = (const _Float16*)ws + (size_t)(wv * 16 + lr) * 64 + oct * 8;
    f16x8 h0f = *(const f16x8*)(s_h116 + lr * 72 + oct * 8);
    f16x8 h1f = *(const f16x8*)(s_h116 + lr * 72 + 32 + oct * 8);
    f32x4 accA = ZERO4, accB = ZERO4;
    #pragma unroll 4
    for (int f = 0; f < 40; ++f) {
      f16x8 b0 = *(const f16x8*)(bb + (size_t)f * 4096);
      f16x8 b1 = *(const f16x8*)(bb + (size_t)f * 4096 + 32);
      _Float16 ov = s_own16[lr * 56 + f];
      f16x8 a0, a1;
      #pragma unroll
      for (int k = 0; k < 8; ++k) { a0[k] = h0f[k] * ov; a1[k] = h1f[k] * ov; }
      if (f & 1) { accB = MFH(a0, b0, accB); accB = MFH(a1, b1, accB); }
      else       { accA = MFH(a0, b0, accA); accA = MFH(a1, b1, accA); }
    }
    {
      f16x8 b0 = *(const f16x8*)(bb + (size_t)40 * 4096);
      f16x8 b1 = *(const f16x8*)(bb + (size_t)40 * 4096 + 32);
      accA = MFH(h0f, b0, accA);
      accA = MFH(h1f, b1, accA);
    }
    {
      f16x8 b0 = *(const f16x8*)(bb + (size_t)41 * 4096);
      f16x8 b1 = *(const f16x8*)(bb + (size_t)41 * 4096 + 32);
      f16x8 a0 = *(const f16x8*)(s_own16 + lr * 56 + oct * 8);
      f16x8 a1;
      if (oct == 0)      a1 = *(const f16x8*)(s_own16 + lr * 56 + 32);
      else if (oct == 1) a1 = ONE8F;
      else               a1 = ZERO8F;
      accB = MFH(a0, b0, accB);
      accB = MFH(a1, b1, accB);
    }
    #pragma unroll
    for (int j = 0; j < 4; ++j)
      s_u16[(oct * 4 + j) * 196 + wv * 16 + lr] = (_Float16)(accA[j] + accB[j]);
  }
  __syncthreads();

  // ---------------- phase 3: MHA via G-trick, full-side LDS residency ------
  #pragma unroll
  for (int side = 0; side < 2; ++side) {
    const int n_ent = side ? 16 : 15;
    const _Float16* woT = (const _Float16*)((const char*)ws + (side ? OFF_WOE : OFF_WOA));
    const _Float16* vbT = (const _Float16*)((const char*)ws + (side ? OFF_VBE : OFF_VBA));
    const _Float16* gT  = (const _Float16*)((const char*)ws + (side ? OFF_GE  : OFF_GA));

    // --- w = own_e @ G -> s_w16 ---
    {
      f16x8 a0 = *(const f16x8*)(s_u16 + lr * 196 + oct * 8);
      f16x8 a1 = *(const f16x8*)(s_u16 + lr * 196 + 32 + oct * 8);
      #pragma unroll
      for (int t2 = 0; t2 < 2; ++t2) {
        int col = wv * 32 + t2 * 16 + lr;
        f16x8 b0 = *(const f16x8*)(gT + col * 64 + oct * 8);
        f16x8 b1 = *(const f16x8*)(gT + col * 64 + 32 + oct * 8);
        f32x4 acc = ZERO4;
        acc = MFH(a0, b0, acc);
        acc = MFH(a1, b1, acc);
        #pragma unroll
        for (int j = 0; j < 4; ++j)
          s_w16[(oct * 4 + j) * 132 + col] = (_Float16)acc[j];
      }
    }
    __syncthreads();

    // --- score: thread (s, n=ln); mask; 16-lane softmax; p -> p16 ---
    {
      float sc0 = -2.0e9f, sc1 = -2.0e9f, sc2 = -2.0e9f, sc3 = -2.0e9f;
      if (ln < n_ent) {
        const char* rb = s_pool + ln * 1088 + s * 68;
        const int x = (ln & 3) << 4;
        union { u32x4 u; f16x8 h; } c0, c1, c2;
        c0.u = *(const u32x4*)(rb + (0  ^ x));
        c1.u = *(const u32x4*)(rb + (16 ^ x));
        c2.u = *(const u32x4*)(rb + (32 ^ x));
        u32x4 orv = c0.u | c1.u | c2.u;
        bool msk = (orv[0] | orv[1] | orv[2] | orv[3]) != 0u;
        const _Float16* wp = s_w16 + s * 132;
        float sc[4];
        #pragma unroll
        for (int h = 0; h < 4; ++h) {
          f16x8 w0 = *(const f16x8*)(wp + h * 32);
          f16x8 w1 = *(const f16x8*)(wp + h * 32 + 8);
          f16x8 w2 = *(const f16x8*)(wp + h * 32 + 16);
          float a = (float)wp[h * 32 + 24];
          #pragma unroll
          for (int k = 0; k < 8; ++k) {
            a += (float)c0.h[k] * (float)w0[k];
            a += (float)c1.h[k] * (float)w1[k];
            a += (float)c2.h[k] * (float)w2[k];
          }
          sc[h] = a;
        }
        if (msk) { sc0 = sc[0]; sc1 = sc[1]; sc2 = sc[2]; sc3 = sc[3]; }
        else     { sc0 = sc1 = sc2 = sc3 = -1.0e9f; }
      }
      float m0 = sc0, m1 = sc1, m2 = sc2, m3 = sc3;
      #pragma unroll
      for (int d = 1; d < 16; d <<= 1) {
        m0 = fmaxf(m0, __shfl_xor(m0, d));
        m1 = fmaxf(m1, __shfl_xor(m1, d));
        m2 = fmaxf(m2, __shfl_xor(m2, d));
        m3 = fmaxf(m3, __shfl_xor(m3, d));
      }
      float p0 = __builtin_exp2f(sc0 - m0);
      float p1 = __builtin_exp2f(sc1 - m1);
      float p2 = __builtin_exp2f(sc2 - m2);
      float p3 = __builtin_exp2f(sc3 - m3);
      float l0 = p0, l1 = p1, l2 = p2, l3 = p3;
      #pragma unroll
      for (int d = 1; d < 16; d <<= 1) {
        l0 += __shfl_xor(l0, d);
        l1 += __shfl_xor(l1, d);
        l2 += __shfl_xor(l2, d);
        l3 += __shfl_xor(l3, d);
      }
      f16x4 pk;
      pk[0] = (_Float16)(p0 * __builtin_amdgcn_rcpf(l0));
      pk[1] = (_Float16)(p1 * __builtin_amdgcn_rcpf(l1));
      pk[2] = (_Float16)(p2 * __builtin_amdgcn_rcpf(l2));
      pk[3] = (_Float16)(p3 * __builtin_amdgcn_rcpf(l3));
      if (ln < n_ent) *(f16x4*)(s_p16 + ln * 72 + s * 4) = pk;
    }
    __syncthreads();

    // --- PV: 16 back-to-back MFMA, p folded into A-frag ---
    {
      f16x8 vbF = *(const f16x8*)(vbT + (wv * 16 + lr) * 32 + oct * 8);
      f32x4 oaccA = ZERO4, oaccB = ZERO4;
      #pragma unroll
      for (int i = 0; i < 16; ++i) {
        if (i >= n_ent) break;
        _Float16 pv = s_p16[i * 72 + lr * 4 + wv];
        f16x8 frag;
        if (oct < 3) {
          f16x8 rv = *(const f16x8*)(s_pool + i * 1088 + lr * 68 + ((oct << 4) ^ ((i & 3) << 4)));
          #pragma unroll
          for (int k = 0; k < 8; ++k) frag[k] = rv[k] * pv;
        } else {
          frag = ZERO8F; frag[0] = pv;
        }
        if (i & 1) oaccB = MFH(frag, vbF, oaccB);
        else       oaccA = MFH(frag, vbF, oaccA);
      }
      __syncthreads();   // rawh/p16 reads done before att overwrites w16 region
      #pragma unroll
      for (int j = 0; j < 4; ++j)
        s_att16[(oct * 4 + j) * 72 + wv * 16 + lr] = (_Float16)(oaccA[j] + oaccB[j]);
    }
    __syncthreads();

    // --- o-GEMM -> u[:, 64+side*64]; stage ENEMY raw during side 0 ---
    {
      f16x8 a0 = *(const f16x8*)(s_att16 + lr * 72 + oct * 8);
      f16x8 a1 = *(const f16x8*)(s_att16 + lr * 72 + 32 + oct * 8);
      f16x8 b0 = *(const f16x8*)(woT + (wv * 16 + lr) * 64 + oct * 8);
      f16x8 b1 = *(const f16x8*)(woT + (wv * 16 + lr) * 64 + 32 + oct * 8);
      f32x4 oa = ZERO4;
      oa = MFH(a0, b0, oa);
      oa = MFH(a1, b1, oa);
      #pragma unroll
      for (int j = 0; j < 4; ++j)
        s_u16[(oct * 4 + j) * 196 + 64 + side * 64 + wv * 16 + lr] = (_Float16)oa[j];
      if (side == 0) {
        for (int i = tid; i < 3072; i += 256) {   // 16*16*12 float2
          int nn = i / 192, r = i - nn * 192, s2 = r / 12, cc = r - s2 * 12;
          float2 v = *(const float2*)(enemy_raw + (size_t)(bs0 + s2) * 384 + nn * 24 + cc * 2);
          f16x2 pk; pk[0] = (_Float16)v.x; pk[1] = (_Float16)v.y;
          int byte = cc * 4;
          int sw = ((((byte >> 4) ^ (nn & 3)) << 4) | (byte & 15));
          *(f16x2*)(s_pool + nn * 1088 + s2 * 68 + sw) = pk;
        }
      }
    }
    __syncthreads();
  }

  // ---------------- phase 4: GRU (f16 MFMA, in-register pointwise) ---------
  {
    const _Float16* ihT = (const _Float16*)((const char*)ws + OFF_GIH);
    const _Float16* hhT = (const _Float16*)((const char*)ws + OFF_GHH);
    const float* gbS = (const float*)((const char*)ws + OFF_GBS);
    const float* gbH = (const float*)((const char*)ws + OFF_GBH);
    f32x4 aX0 = ZERO4, aX1 = ZERO4, aX2 = ZERO4, aH2 = ZERO4;
    #pragma unroll
    for (int st = 0; st < 6; ++st) {
      f16x8 uf = *(const f16x8*)(s_u16 + lr * 196 + st * 32 + oct * 8);
      f16x8 b0 = *(const f16x8*)(ihT + ((wv    ) * 16 + lr) * 192 + st * 32 + oct * 8);
      f16x8 b1 = *(const f16x8*)(ihT + ((wv + 4) * 16 + lr) * 192 + st * 32 + oct * 8);
      f16x8 b2 = *(const f16x8*)(ihT + ((wv + 8) * 16 + lr) * 192 + st * 32 + oct * 8);
      aX0 = MFH(uf, b0, aX0);
      aX1 = MFH(uf, b1, aX1);
      aX2 = MFH(uf, b2, aX2);
    }
    #pragma unroll
    for (int st = 0; st < 2; ++st) {
      f16x8 hf = *(const f16x8*)(s_hid16 + lr * 68 + st * 32 + oct * 8);
      f16x8 b0 = *(const f16x8*)(hhT + ((wv    ) * 16 + lr) * 64 + st * 32 + oct * 8);
      f16x8 b1 = *(const f16x8*)(hhT + ((wv + 4) * 16 + lr) * 64 + st * 32 + oct * 8);
      f16x8 b2 = *(const f16x8*)(hhT + ((wv + 8) * 16 + lr) * 64 + st * 32 + oct * 8);
      aX0 = MFH(hf, b0, aX0);
      aX1 = MFH(hf, b1, aX1);
      aH2 = MFH(hf, b2, aH2);
    }
    const int c0 = wv * 16 + lr;
    float bb0 = gbS[c0], bb1 = gbS[c0 + 64], bb2 = gbS[c0 + 128], bbh = gbH[c0];
    #pragma unroll
    for (int j = 0; j < 4; ++j) {
      int row = oct * 4 + j;
      float xr = aX0[j] + bb0;
      float xz = aX1[j] + bb1;
      float xn = aX2[j] + bb2;
      float hn = aH2[j] + bbh;
      float r  = __builtin_amdgcn_rcpf(1.f + __builtin_exp2f(-xr * LOG2E));
      float zg = __builtin_amdgcn_rcpf(1.f + __builtin_exp2f(-xz * LOG2E));
      float ta = xn + r * hn;
      float nc = 1.f - 2.f * __builtin_amdgcn_rcpf(1.f + __builtin_exp2f(2.f * LOG2E * ta));
      float hv = (float)s_hid16[row * 68 + c0];
      s_z16[row * 72 + c0] = (_Float16)((1.f - zg) * nc + zg * hv);
    }
  }
  __syncthreads();

  // ---------------- phase 5: fused head GEMM (waves 0,1) -------------------
  {
    const _Float16* bhT = (const _Float16*)((const char*)ws + OFF_BHD);
    if (wv < 2) {
      f16x8 a0 = *(const f16x8*)(s_z16 + lr * 72 + oct * 8);
      f16x8 a1 = *(const f16x8*)(s_z16 + lr * 72 + 32 + oct * 8);
      f16x8 b0 = *(const f16x8*)(bhT + (wv * 16 + lr) * 64 + oct * 8);
      f16x8 b1 = *(const f16x8*)(bhT + (wv * 16 + lr) * 64 + 32 + oct * 8);
      f32x4 td = ZERO4;
      td = MFH(a0, b0, td);
      td = MFH(a1, b1, td);
      const int col = wv * 16 + lr;
      #pragma unroll
      for (int j = 0; j < 4; ++j) {
        int row = oct * 4 + j;
        if (col < 25)      s_t[row * 26 + col] = td[j];
        else if (col < 31) s_q[row * 22 + (col - 25)] = td[j] + bm[col - 25];
      }
    }
  }
  __syncthreads();
  // shoot logits from LDS-resident enemy raw (f16) + t
  {
    const char* rb = s_pool + ln * 1088 + s * 68;
    const int x = (ln & 3) << 4;
    f16x8 r0 = *(const f16x8*)(rb + (0  ^ x));
    f16x8 r1 = *(const f16x8*)(rb + (16 ^ x));
    f16x8 r2 = *(const f16x8*)(rb + (32 ^ x));
    const float* tp = s_t + s * 26;
    float acc2 = tp[24];
    #pragma unroll
    for (int k = 0; k < 8; ++k) {
      acc2 += (float)r0[k] * tp[k];
      acc2 += (float)r1[k] * tp[8 + k];
      acc2 += (float)r2[k] * tp[16 + k];
    }
    s_q[s * 22 + 6 + ln] = acc2;
  }
  __syncthreads();
  // coalesced output tail
  for (int i = tid; i < 352; i += 256)
    out[(size_t)bs0 * 22 + i] = s_q[i];
  for (int i = tid; i < 1024; i += 256)
    out[(size_t)BN * 22 + (size_t)bs0 * 64 + i] = (float)s_z16[(i >> 6) * 72 + (i & 63)];
}

// ============================================================= launch =======
extern "C" void kernel_launch(void* const* d_in, const int* in_sizes, int n_in,
                              void* d_out, int out_size, void* d_ws, size_t ws_size,
                              hipStream_t stream) {
  (void)n_in; (void)out_size; (void)ws_size;
  const float* own_raw   = (const float*)d_in[0];
  const float* ally_raw  = (const float*)d_in[1];
  const float* enemy_raw = (const float*)d_in[2];
  const float* hidden    = (const float*)d_in[3];
  const float* hyp_W1    = (const float*)d_in[4];
  const float* hyp_b1    = (const float*)d_in[5];
  const float* hyp_W2    = (const float*)d_in[6];
  const float* hyp_b2    = (const float*)d_in[7];
  const float* Wa        = (const float*)d_in[8];
  const float* ba        = (const float*)d_in[9];
  const float* We        = (const float*)d_in[10];
  const float* be        = (const float*)d_in[11];
  const float* aWq       = (const float*)d_in[12];
  const float* aWk       = (const float*)d_in[13];
  const float* aWv       = (const float*)d_in[14];
  const float* aWo       = (const float*)d_in[15];
  const float* eWq       = (const float*)d_in[16];
  const float* eWk       = (const float*)d_in[17];
  const float* eWv       = (const float*)d_in[18];
  const float* eWo       = (const float*)d_in[19];
  const float* gWih      = (const float*)d_in[20];
  const float* gWhh      = (const float*)d_in[21];
  const float* gbih      = (const float*)d_in[22];
  const float* gbhh      = (const float*)d_in[23];
  const float* Wm        = (const float*)d_in[24];
  const float* bm        = (const float*)d_in[25];
  const float* WzK       = (const float*)d_in[26];
  const float* WEK       = (const float*)d_in[27];
  int BN = in_sizes[0] / 40;
  int blocks = BN / TB;

  hipLaunchKernelGGL(prep_kernel, dim3(53), dim3(256), 0, stream,
                     hyp_W1, hyp_b1, hyp_W2, hyp_b2, Wa, ba, We, be,
                     aWq, aWk, aWv, aWo, eWq, eWk, eWv, eWo,
                     gWih, gWhh, gbih, gbhh, WzK, WEK, Wm, d_ws);
  hipLaunchKernelGGL(agent_kernel, dim3(blocks), dim3(256), 0, stream,
                     own_raw, ally_raw, enemy_raw, hidden, bm,
                     d_ws, (float*)d_out, BN);
}

// Round 8
// 183.849 us; speedup vs baseline: 1.1953x; 1.0534x over previous
//
#include <hip/hip_runtime.h>
#include <hip/hip_bf16.h>
#include <math.h>

#define TB 16
#define LOG2E 1.44269504f

typedef float f32x4 __attribute__((ext_vector_type(4)));
typedef _Float16 f16x8 __attribute__((ext_vector_type(8)));
typedef _Float16 f16x4 __attribute__((ext_vector_type(4)));
typedef _Float16 f16x2 __attribute__((ext_vector_type(2)));
typedef unsigned int u32x4 __attribute__((ext_vector_type(4)));

// ---------------- ws layout (bytes), all weight mats f16 [col][k] -----------
#define OFF_W1T  344064
#define OFF_WOA  352256   // [64][64] = aWo^T
#define OFF_WOE  360448   // [64][64] = eWo^T
#define OFF_VBA  368640   // [64h][32k] = We@Wv fused (k=24 bias row)
#define OFF_VBE  372736
#define OFF_GA   376832   // [128][64]
#define OFF_GE   393216
#define OFF_GIH  409600
#define OFF_GHH  483328
#define OFF_GBS  507904
#define OFF_GBH  508672
#define OFF_BHD  508928

#define MFH(a, b, c) __builtin_amdgcn_mfma_f32_16x16x32_f16((a), (b), (c), 0, 0, 0)

__device__ inline f16x2 u2h(unsigned u) {
  union { unsigned x; f16x2 h; } c; c.x = u; return c.h;
}
__device__ inline float dot2(f16x2 a, f16x2 b, float c) {
#if __has_builtin(__builtin_amdgcn_fdot2)
  return __builtin_amdgcn_fdot2(a, b, c, false);
#else
  return c + (float)a[0] * (float)b[0] + (float)a[1] * (float)b[1];
#endif
}

// ============================================================= prep =========
__global__ __launch_bounds__(256)
void prep_kernel(const float* __restrict__ hyp_W1, const float* __restrict__ hyp_b1,
                 const float* __restrict__ hyp_W2, const float* __restrict__ hyp_b2,
                 const float* __restrict__ Wa, const float* __restrict__ ba,
                 const float* __restrict__ We, const float* __restrict__ be,
                 const float* __restrict__ aWq, const float* __restrict__ aWk,
                 const float* __restrict__ aWv, const float* __restrict__ aWo,
                 const float* __restrict__ eWq, const float* __restrict__ eWk,
                 const float* __restrict__ eWv, const float* __restrict__ eWo,
                 const float* __restrict__ gWih, const float* __restrict__ gWhh,
                 const float* __restrict__ gbih, const float* __restrict__ gbhh,
                 const float* __restrict__ WzK, const float* __restrict__ WEK,
                 const float* __restrict__ Wm,
                 void* __restrict__ ws)
{
  const int b = blockIdx.x, t = threadIdx.x;
  if (b < 42) {
    _Float16* o = (_Float16*)ws;
    for (int i = t; i < 4096; i += 256) {
      int h = i >> 6, k = i & 63;
      float v;
      if (b < 40)       v = hyp_W2[(size_t)k * 2628 + b * 64 + h];
      else if (b == 40) v = hyp_W2[(size_t)k * 2628 + 2560 + h];
      else              v = (k < 40) ? hyp_b2[k * 64 + h]
                             : (k == 40 ? hyp_b2[2560 + h] : 0.0f);
      o[b * 4096 + i] = (_Float16)v;
    }
  } else if (b == 42) {
    _Float16* o = (_Float16*)((char*)ws + OFF_W1T);
    for (int i = t; i < 4096; i += 256) {
      int h = i >> 6, k = i & 63;
      float v = (k < 40) ? hyp_W1[k * 64 + h] : (k == 40 ? hyp_b1[h] : 0.0f);
      o[i] = (_Float16)v;
    }
  } else if (b == 43 || b == 44) {
    const float* M = (b == 43) ? aWo : eWo;
    _Float16* o = (_Float16*)((char*)ws + (b == 43 ? OFF_WOA : OFF_WOE));
    for (int i = t; i < 4096; i += 256)
      o[i] = (_Float16)M[(i & 63) * 64 + (i >> 6)];
  } else if (b == 45 || b == 46) {
    // Vb = [Wemb|bemb] @ Wv   (NO Wo fold — accuracy)
    const float* Wemb = (b == 45) ? Wa : We;
    const float* bemb = (b == 45) ? ba : be;
    const float* Wv   = (b == 45) ? aWv : eWv;
    _Float16* o = (_Float16*)((char*)ws + (b == 45 ? OFF_VBA : OFF_VBE));
    for (int i = t; i < 2048; i += 256) {
      int h = i >> 5, k = i & 31;
      float v = 0.f;
      if (k < 24)       { for (int d = 0; d < 64; ++d) v += Wemb[k * 64 + d] * Wv[d * 64 + h]; }
      else if (k == 24) { for (int d = 0; d < 64; ++d) v += bemb[d] * Wv[d * 64 + h]; }
      o[i] = (_Float16)v;
    }
  } else if (b == 47 || b == 48) {
    const float* Wemb = (b == 47) ? Wa : We;
    const float* bemb = (b == 47) ? ba : be;
    const float* Wk   = (b == 47) ? aWk : eWk;
    const float* Wq   = (b == 47) ? aWq : eWq;
    _Float16* o = (_Float16*)((char*)ws + (b == 47 ? OFF_GA : OFF_GE));
    __shared__ float sKb[25 * 64];
    for (int i = t; i < 1600; i += 256) {
      int k = i >> 6, c = i & 63;
      float v = 0.f;
      if (k < 24)  { for (int d = 0; d < 64; ++d) v += Wemb[k * 64 + d] * Wk[d * 64 + c]; }
      else         { for (int d = 0; d < 64; ++d) v += bemb[d] * Wk[d * 64 + c]; }
      sKb[i] = v;
    }
    __syncthreads();
    for (int i = t; i < 8192; i += 256) {
      int col = i >> 6, d = i & 63;
      int h = col >> 5, kk = col & 31;
      float v = 0.f;
      if (kk < 25)
        for (int dh = 0; dh < 16; ++dh)
          v += Wq[d * 64 + h * 16 + dh] * sKb[kk * 64 + h * 16 + dh];
      o[i] = (_Float16)(v * 0.25f * LOG2E);
    }
  } else if (b == 49) {
    _Float16* o = (_Float16*)((char*)ws + OFF_GIH);
    for (int i = t; i < 36864; i += 256) {
      int d = i / 192, c = i - d * 192;
      o[c * 192 + d] = (_Float16)gWih[i];
    }
  } else if (b == 50) {
    _Float16* o = (_Float16*)((char*)ws + OFF_GHH);
    for (int i = t; i < 12288; i += 256) {
      int d = i / 192, c = i - d * 192;
      o[c * 64 + d] = (_Float16)gWhh[i];
    }
  } else if (b == 51) {
    float* gbS = (float*)((char*)ws + OFF_GBS);
    float* gbH = (float*)((char*)ws + OFF_GBH);
    if (t < 192) gbS[t] = gbih[t] + (t < 128 ? gbhh[t] : 0.0f);
    if (t < 64)  gbH[t] = gbhh[128 + t];
  } else if (b == 52) { // head B-matrix
    __shared__ float sWsK[24 * 64];
    __shared__ float sbw[64];
    _Float16* o = (_Float16*)((char*)ws + OFF_BHD);
    for (int i = t; i < 1536; i += 256) {
      int j = i >> 6, h = i & 63;
      float v = 0.f;
      for (int c = 0; c < 64; ++c) v += We[j * 64 + c] * WEK[c * 64 + h];
      sWsK[i] = v;
    }
    if (t < 64) {
      float v = 0.f;
      for (int c = 0; c < 64; ++c) v += be[c] * WEK[c * 64 + t];
      sbw[t] = v;
    }
    __syncthreads();
    for (int i = t; i < 2048; i += 256) {
      int col = i >> 6, c = i & 63;
      float v = 0.f;
      if (col < 24)       { for (int d = 0; d < 64; ++d) v += WzK[c * 64 + d] * sWsK[col * 64 + d]; }
      else if (col == 24) { for (int d = 0; d < 64; ++d) v += WzK[c * 64 + d] * sbw[d]; }
      else if (col < 31)  v = Wm[c * 6 + (col - 25)];
      o[i] = (_Float16)v;
    }
  }
}

// ============================================================= main =========
__global__ __launch_bounds__(256, 5)
void agent_kernel(
    const float* __restrict__ own_raw, const float* __restrict__ ally_raw,
    const float* __restrict__ enemy_raw, const float* __restrict__ hidden,
    const float* __restrict__ bm,
    const void* __restrict__ ws,
    float* __restrict__ out, int BN)
{
  __shared__ _Float16 s_u16[TB * 196];       // own_e | zA | zE
  __shared__ _Float16 s_hid16[TB * 68];
  __shared__ __align__(16) char s_pool[24064];
  // 0..17408      rawh [16n][16s][34] f16, 16B-chunk XOR-swizzled by (n&3)
  // 17408..24064  R2:
  //   ph0-2: own16 @+0 (1792) | ownT f32 @+1792 (2560) | h116 @+4352 (2304)
  //   ph3  : w16 @+0 (4224)   | p16 @+4224 (2304) | att16 @+0 post-PV (2304)
  //   ph4+ : z16 @+0 (2304)   | s_t @+2304 (1664) | s_q @+3968 (1408)

  const int tid = threadIdx.x;
  const int bs0 = blockIdx.x * TB;
  const int s   = tid >> 4;
  const int ln  = tid & 15;
  const int l   = tid & 63;
  const int wv  = tid >> 6;
  const int lr  = l & 15;
  const int oct = l >> 4;

  _Float16* s_own16 = (_Float16*)(s_pool + 17408);
  float*    s_ownT  = (float*)(s_pool + 17408 + 1792);
  _Float16* s_h116  = (_Float16*)(s_pool + 17408 + 4352);
  _Float16* s_w16   = (_Float16*)(s_pool + 17408);
  _Float16* s_att16 = (_Float16*)(s_pool + 17408);
  _Float16* s_p16   = (_Float16*)(s_pool + 17408 + 4224);
  _Float16* s_z16   = (_Float16*)(s_pool + 17408);
  float*    s_t     = (float*)(s_pool + 17408 + 2304);
  float*    s_q     = (float*)(s_pool + 17408 + 3968);

  const f16x8 ZERO8F = {0,0,0,0,0,0,0,0};
  f16x8 ONE8F = ZERO8F; ONE8F[0] = (_Float16)1.0f;
  const f32x4 ZERO4 = {0.f, 0.f, 0.f, 0.f};

  // ---------------- phase 0: stage own (f16 + f32-T) + hidden + ALLY -------
  for (int i = tid; i < 320; i += 256) {
    int ss = i / 20, c = i - ss * 20;
    float2 v = *(const float2*)(own_raw + (size_t)(bs0 + ss) * 40 + c * 2);
    f16x2 pk; pk[0] = (_Float16)v.x; pk[1] = (_Float16)v.y;
    *(f16x2*)(s_own16 + ss * 56 + c * 2) = pk;
  }
  for (int i = tid; i < 640; i += 256) {       // ownT[f][s] f32
    int f = i >> 4, s2 = i & 15;
    s_ownT[i] = own_raw[(size_t)(bs0 + s2) * 40 + f];
  }
  for (int i = tid; i < 512; i += 256) {
    int ss = i >> 5, c = i & 31;
    float2 v = *(const float2*)(hidden + (size_t)(bs0 + ss) * 64 + c * 2);
    f16x2 pk; pk[0] = (_Float16)v.x; pk[1] = (_Float16)v.y;
    *(f16x2*)(s_hid16 + ss * 68 + c * 2) = pk;
  }
  for (int i = tid; i < 2880; i += 256) {      // ally: 15*16*12 float2
    int nn = i / 192, r = i - nn * 192, s2 = r / 12, cc = r - s2 * 12;
    float2 v = *(const float2*)(ally_raw + (size_t)(bs0 + s2) * 360 + nn * 24 + cc * 2);
    f16x2 pk; pk[0] = (_Float16)v.x; pk[1] = (_Float16)v.y;
    int byte = cc * 4;
    int sw = ((((byte >> 4) ^ (nn & 3)) << 4) | (byte & 15));
    *(f16x2*)(s_pool + nn * 1088 + s2 * 68 + sw) = pk;
  }
  __syncthreads();

  // ---------------- phase 1: h1 = relu(own @ W1 + b1) ----------------
  {
    const _Float16* w1t = (const _Float16*)((const char*)ws + OFF_W1T);
    f16x8 a0 = *(const f16x8*)(s_own16 + lr * 56 + oct * 8);
    f16x8 a1;
    if (oct == 0)      a1 = *(const f16x8*)(s_own16 + lr * 56 + 32);
    else if (oct == 1) a1 = ONE8F;
    else               a1 = ZERO8F;
    f16x8 b0 = *(const f16x8*)(w1t + (wv * 16 + lr) * 64 + oct * 8);
    f16x8 b1 = *(const f16x8*)(w1t + (wv * 16 + lr) * 64 + 32 + oct * 8);
    f32x4 acc = ZERO4;
    acc = MFH(a0, b0, acc);
    acc = MFH(a1, b1, acc);
    #pragma unroll
    for (int j = 0; j < 4; ++j)
      s_h116[(oct * 4 + j) * 72 + wv * 16 + lr] = (_Float16)fmaxf(acc[j], 0.f);
  }
  __syncthreads();

  // ---------------- phase 2: own_e, scale-in-accumulator -------------------
  {
    const _Float16* bb = (const _Float16*)ws + (size_t)(wv * 16 + lr) * 64 + oct * 8;
    f16x8 h0f = *(const f16x8*)(s_h116 + lr * 72 + oct * 8);
    f16x8 h1f = *(const f16x8*)(s_h116 + lr * 72 + 32 + oct * 8);
    f32x4 acc = ZERO4;
    #pragma unroll 4
    for (int f = 0; f < 40; ++f) {
      f16x8 b0 = *(const f16x8*)(bb + (size_t)f * 4096);
      f16x8 b1 = *(const f16x8*)(bb + (size_t)f * 4096 + 32);
      f32x4 y = MFH(h0f, b0, ZERO4);
      y = MFH(h1f, b1, y);
      float4 ov4 = *(const float4*)(s_ownT + f * 16 + oct * 4);  // LDS broadcast
      acc[0] += ov4.x * y[0];
      acc[1] += ov4.y * y[1];
      acc[2] += ov4.z * y[2];
      acc[3] += ov4.w * y[3];
    }
    f32x4 accD = ZERO4;
    { // f=40 (h1 tile, ov=1)
      f16x8 b0 = *(const f16x8*)(bb + (size_t)40 * 4096);
      f16x8 b1 = *(const f16x8*)(bb + (size_t)40 * 4096 + 32);
      accD = MFH(h0f, b0, accD);
      accD = MFH(h1f, b1, accD);
    }
    { // f=41 ([own | 1 | 0] bias tile)
      f16x8 b0 = *(const f16x8*)(bb + (size_t)41 * 4096);
      f16x8 b1 = *(const f16x8*)(bb + (size_t)41 * 4096 + 32);
      f16x8 a0 = *(const f16x8*)(s_own16 + lr * 56 + oct * 8);
      f16x8 a1;
      if (oct == 0)      a1 = *(const f16x8*)(s_own16 + lr * 56 + 32);
      else if (oct == 1) a1 = ONE8F;
      else               a1 = ZERO8F;
      accD = MFH(a0, b0, accD);
      accD = MFH(a1, b1, accD);
    }
    #pragma unroll
    for (int j = 0; j < 4; ++j)
      s_u16[(oct * 4 + j) * 196 + wv * 16 + lr] = (_Float16)(acc[j] + accD[j]);
  }
  __syncthreads();

  // ---------------- phase 3: MHA (G-trick, separate o-GEMM) ----------------
  #pragma unroll
  for (int side = 0; side < 2; ++side) {
    const int n_ent = side ? 16 : 15;
    const _Float16* woT = (const _Float16*)((const char*)ws + (side ? OFF_WOE : OFF_WOA));
    const _Float16* vbT = (const _Float16*)((const char*)ws + (side ? OFF_VBE : OFF_VBA));
    const _Float16* gT  = (const _Float16*)((const char*)ws + (side ? OFF_GE  : OFF_GA));

    // --- w = own_e @ G -> w16; stage enemy raw during side 1's w-GEMM ---
    {
      f16x8 a0 = *(const f16x8*)(s_u16 + lr * 196 + oct * 8);
      f16x8 a1 = *(const f16x8*)(s_u16 + lr * 196 + 32 + oct * 8);
      #pragma unroll
      for (int t2 = 0; t2 < 2; ++t2) {
        int col = wv * 32 + t2 * 16 + lr;
        f16x8 b0 = *(const f16x8*)(gT + col * 64 + oct * 8);
        f16x8 b1 = *(const f16x8*)(gT + col * 64 + 32 + oct * 8);
        f32x4 acc = ZERO4;
        acc = MFH(a0, b0, acc);
        acc = MFH(a1, b1, acc);
        #pragma unroll
        for (int j = 0; j < 4; ++j)
          s_w16[(oct * 4 + j) * 132 + col] = (_Float16)acc[j];
      }
      if (side == 1) {
        for (int i = tid; i < 3072; i += 256) {   // enemy: 16*16*12 float2
          int nn = i / 192, r = i - nn * 192, s2 = r / 12, cc = r - s2 * 12;
          float2 v = *(const float2*)(enemy_raw + (size_t)(bs0 + s2) * 384 + nn * 24 + cc * 2);
          f16x2 pk; pk[0] = (_Float16)v.x; pk[1] = (_Float16)v.y;
          int byte = cc * 4;
          int sw = ((((byte >> 4) ^ (nn & 3)) << 4) | (byte & 15));
          *(f16x2*)(s_pool + nn * 1088 + s2 * 68 + sw) = pk;
        }
      }
    }
    __syncthreads();

    // --- score: thread (s, n=ln); fdot2; 16-lane softmax; p -> p16 ---
    {
      float sc0 = -2.0e9f, sc1 = -2.0e9f, sc2 = -2.0e9f, sc3 = -2.0e9f;
      if (ln < n_ent) {
        const char* rb = s_pool + ln * 1088 + s * 68;
        const int x = (ln & 3) << 4;
        u32x4 c0 = *(const u32x4*)(rb + (0  ^ x));
        u32x4 c1 = *(const u32x4*)(rb + (16 ^ x));
        u32x4 c2 = *(const u32x4*)(rb + (32 ^ x));
        u32x4 orv = c0 | c1 | c2;
        bool msk = (orv[0] | orv[1] | orv[2] | orv[3]) != 0u;
        const _Float16* wp = s_w16 + s * 132;
        float sc[4];
        #pragma unroll
        for (int h = 0; h < 4; ++h) {
          float a = (float)wp[h * 32 + 24];
          #pragma unroll
          for (int p = 0; p < 4; ++p) {
            a = dot2(u2h(c0[p]), *(const f16x2*)(wp + h * 32 + 2 * p), a);
            a = dot2(u2h(c1[p]), *(const f16x2*)(wp + h * 32 + 8 + 2 * p), a);
            a = dot2(u2h(c2[p]), *(const f16x2*)(wp + h * 32 + 16 + 2 * p), a);
          }
          sc[h] = a;
        }
        if (msk) { sc0 = sc[0]; sc1 = sc[1]; sc2 = sc[2]; sc3 = sc[3]; }
        else     { sc0 = sc1 = sc2 = sc3 = -1.0e9f; }
      }
      float m0 = sc0, m1 = sc1, m2 = sc2, m3 = sc3;
      #pragma unroll
      for (int d = 1; d < 16; d <<= 1) {
        m0 = fmaxf(m0, __shfl_xor(m0, d));
        m1 = fmaxf(m1, __shfl_xor(m1, d));
        m2 = fmaxf(m2, __shfl_xor(m2, d));
        m3 = fmaxf(m3, __shfl_xor(m3, d));
      }
      float p0 = __builtin_exp2f(sc0 - m0);
      float p1 = __builtin_exp2f(sc1 - m1);
      float p2 = __builtin_exp2f(sc2 - m2);
      float p3 = __builtin_exp2f(sc3 - m3);
      float l0 = p0, l1 = p1, l2 = p2, l3 = p3;
      #pragma unroll
      for (int d = 1; d < 16; d <<= 1) {
        l0 += __shfl_xor(l0, d);
        l1 += __shfl_xor(l1, d);
        l2 += __shfl_xor(l2, d);
        l3 += __shfl_xor(l3, d);
      }
      f16x4 pk;
      pk[0] = (_Float16)(p0 * __builtin_amdgcn_rcpf(l0));
      pk[1] = (_Float16)(p1 * __builtin_amdgcn_rcpf(l1));
      pk[2] = (_Float16)(p2 * __builtin_amdgcn_rcpf(l2));
      pk[3] = (_Float16)(p3 * __builtin_amdgcn_rcpf(l3));
      if (ln < n_ent) *(f16x4*)(s_p16 + ln * 72 + s * 4) = pk;
    }
    __syncthreads();

    // --- PV: 16 back-to-back MFMA -> att16 (w16 dead after score) ---
    {
      f16x8 vbF = *(const f16x8*)(vbT + (wv * 16 + lr) * 32 + oct * 8);
      f32x4 oaccA = ZERO4, oaccB = ZERO4;
      #pragma unroll
      for (int i = 0; i < 16; ++i) {
        if (i >= n_ent) break;
        _Float16 pv = s_p16[i * 72 + lr * 4 + wv];
        f16x8 frag;
        if (oct < 3) {
          f16x8 rv = *(const f16x8*)(s_pool + i * 1088 + lr * 68 + ((oct << 4) ^ ((i & 3) << 4)));
          #pragma unroll
          for (int k = 0; k < 8; ++k) frag[k] = rv[k] * pv;
        } else {
          frag = ZERO8F; frag[0] = pv;
        }
        if (i & 1) oaccB = MFH(frag, vbF, oaccB);
        else       oaccA = MFH(frag, vbF, oaccA);
      }
      #pragma unroll
      for (int j = 0; j < 4; ++j)
        s_att16[(oct * 4 + j) * 72 + wv * 16 + lr] = (_Float16)(oaccA[j] + oaccB[j]);
    }
    __syncthreads();

    // --- o-GEMM -> u[:, 64+side*64] ---
    {
      f16x8 a0 = *(const f16x8*)(s_att16 + lr * 72 + oct * 8);
      f16x8 a1 = *(const f16x8*)(s_att16 + lr * 72 + 32 + oct * 8);
      f16x8 b0 = *(const f16x8*)(woT + (wv * 16 + lr) * 64 + oct * 8);
      f16x8 b1 = *(const f16x8*)(woT + (wv * 16 + lr) * 64 + 32 + oct * 8);
      f32x4 oa = ZERO4;
      oa = MFH(a0, b0, oa);
      oa = MFH(a1, b1, oa);
      #pragma unroll
      for (int j = 0; j < 4; ++j)
        s_u16[(oct * 4 + j) * 196 + 64 + side * 64 + wv * 16 + lr] = (_Float16)oa[j];
    }
    __syncthreads();
  }

  // ---------------- phase 4: GRU (f16 MFMA, in-register pointwise) ---------
  {
    const _Float16* ihT = (const _Float16*)((const char*)ws + OFF_GIH);
    const _Float16* hhT = (const _Float16*)((const char*)ws + OFF_GHH);
    const float* gbS = (const float*)((const char*)ws + OFF_GBS);
    const float* gbH = (const float*)((const char*)ws + OFF_GBH);
    f32x4 aX0 = ZERO4, aX1 = ZERO4, aX2 = ZERO4, aH2 = ZERO4;
    #pragma unroll
    for (int st = 0; st < 6; ++st) {
      f16x8 uf = *(const f16x8*)(s_u16 + lr * 196 + st * 32 + oct * 8);
      f16x8 b0 = *(const f16x8*)(ihT + ((wv    ) * 16 + lr) * 192 + st * 32 + oct * 8);
      f16x8 b1 = *(const f16x8*)(ihT + ((wv + 4) * 16 + lr) * 192 + st * 32 + oct * 8);
      f16x8 b2 = *(const f16x8*)(ihT + ((wv + 8) * 16 + lr) * 192 + st * 32 + oct * 8);
      aX0 = MFH(uf, b0, aX0);
      aX1 = MFH(uf, b1, aX1);
      aX2 = MFH(uf, b2, aX2);
    }
    #pragma unroll
    for (int st = 0; st < 2; ++st) {
      f16x8 hf = *(const f16x8*)(s_hid16 + lr * 68 + st * 32 + oct * 8);
      f16x8 b0 = *(const f16x8*)(hhT + ((wv    ) * 16 + lr) * 64 + st * 32 + oct * 8);
      f16x8 b1 = *(const f16x8*)(hhT + ((wv + 4) * 16 + lr) * 64 + st * 32 + oct * 8);
      f16x8 b2 = *(const f16x8*)(hhT + ((wv + 8) * 16 + lr) * 64 + st * 32 + oct * 8);
      aX0 = MFH(hf, b0, aX0);
      aX1 = MFH(hf, b1, aX1);
      aH2 = MFH(hf, b2, aH2);
    }
    const int c0 = wv * 16 + lr;
    float bb0 = gbS[c0], bb1 = gbS[c0 + 64], bb2 = gbS[c0 + 128], bbh = gbH[c0];
    #pragma unroll
    for (int j = 0; j < 4; ++j) {
      int row = oct * 4 + j;
      float xr = aX0[j] + bb0;
      float xz = aX1[j] + bb1;
      float xn = aX2[j] + bb2;
      float hn = aH2[j] + bbh;
      float r  = __builtin_amdgcn_rcpf(1.f + __builtin_exp2f(-xr * LOG2E));
      float zg = __builtin_amdgcn_rcpf(1.f + __builtin_exp2f(-xz * LOG2E));
      float ta = xn + r * hn;
      float nc = 1.f - 2.f * __builtin_amdgcn_rcpf(1.f + __builtin_exp2f(2.f * LOG2E * ta));
      float hv = (float)s_hid16[row * 68 + c0];
      s_z16[row * 72 + c0] = (_Float16)((1.f - zg) * nc + zg * hv);
    }
  }
  __syncthreads();

  // ---------------- phase 5: fused head GEMM (waves 0,1) -------------------
  {
    const _Float16* bhT = (const _Float16*)((const char*)ws + OFF_BHD);
    if (wv < 2) {
      f16x8 a0 = *(const f16x8*)(s_z16 + lr * 72 + oct * 8);
      f16x8 a1 = *(const f16x8*)(s_z16 + lr * 72 + 32 + oct * 8);
      f16x8 b0 = *(const f16x8*)(bhT + (wv * 16 + lr) * 64 + oct * 8);
      f16x8 b1 = *(const f16x8*)(bhT + (wv * 16 + lr) * 64 + 32 + oct * 8);
      f32x4 td = ZERO4;
      td = MFH(a0, b0, td);
      td = MFH(a1, b1, td);
      const int col = wv * 16 + lr;
      #pragma unroll
      for (int j = 0; j < 4; ++j) {
        int row = oct * 4 + j;
        if (col < 25)      s_t[row * 26 + col] = td[j];
        else if (col < 31) s_q[row * 22 + (col - 25)] = td[j] + bm[col - 25];
      }
    }
  }
  __syncthreads();
  // shoot logits from LDS-resident enemy raw + t
  {
    const char* rb = s_pool + ln * 1088 + s * 68;
    const int x = (ln & 3) << 4;
    f16x8 r0 = *(const f16x8*)(rb + (0  ^ x));
    f16x8 r1 = *(const f16x8*)(rb + (16 ^ x));
    f16x8 r2 = *(const f16x8*)(rb + (32 ^ x));
    const float* tp = s_t + s * 26;
    float acc2 = tp[24];
    #pragma unroll
    for (int k = 0; k < 8; ++k) {
      acc2 += (float)r0[k] * tp[k];
      acc2 += (float)r1[k] * tp[8 + k];
      acc2 += (float)r2[k] * tp[16 + k];
    }
    s_q[s * 22 + 6 + ln] = acc2;
  }
  __syncthreads();
  // coalesced output tail
  for (int i = tid; i < 352; i += 256)
    out[(size_t)bs0 * 22 + i] = s_q[i];
  for (int i = tid; i < 1024; i += 256)
    out[(size_t)BN * 22 + (size_t)bs0 * 64 + i] = (float)s_z16[(i >> 6) * 72 + (i & 63)];
}

// ============================================================= launch =======
extern "C" void kernel_launch(void* const* d_in, const int* in_sizes, int n_in,
                              void* d_out, int out_size, void* d_ws, size_t ws_size,
                              hipStream_t stream) {
  (void)n_in; (void)out_size; (void)ws_size;
  const float* own_raw   = (const float*)d_in[0];
  const float* ally_raw  = (const float*)d_in[1];
  const float* enemy_raw = (const float*)d_in[2];
  const float* hidden    = (const float*)d_in[3];
  const float* hyp_W1    = (const float*)d_in[4];
  const float* hyp_b1    = (const float*)d_in[5];
  const float* hyp_W2    = (const float*)d_in[6];
  const float* hyp_b2    = (const float*)d_in[7];
  const float* Wa        = (const float*)d_in[8];
  const float* ba        = (const float*)d_in[9];
  const float* We        = (const float*)d_in[10];
  const float* be        = (const float*)d_in[11];
  const float* aWq       = (const float*)d_in[12];
  const float* aWk       = (const float*)d_in[13];
  const float* aWv       = (const float*)d_in[14];
  const float* aWo       = (const float*)d_in[15];
  const float* eWq       = (const float*)d_in[16];
  const float* eWk       = (const float*)d_in[17];
  const float* eWv       = (const float*)d_in[18];
  const float* eWo       = (const float*)d_in[19];
  const float* gWih      = (const float*)d_in[20];
  const float* gWhh      = (const float*)d_in[21];
  const float* gbih      = (const float*)d_in[22];
  const float* gbhh      = (const float*)d_in[23];
  const float* Wm        = (const float*)d_in[24];
  const float* bm        = (const float*)d_in[25];
  const float* WzK       = (const float*)d_in[26];
  const float* WEK       = (const float*)d_in[27];
  int BN = in_sizes[0] / 40;
  int blocks = BN / TB;

  hipLaunchKernelGGL(prep_kernel, dim3(53), dim3(256), 0, stream,
                     hyp_W1, hyp_b1, hyp_W2, hyp_b2, Wa, ba, We, be,
                     aWq, aWk, aWv, aWo, eWq, eWk, eWv, eWo,
                     gWih, gWhh, gbih, gbhh, WzK, WEK, Wm, d_ws);
  hipLaunchKernelGGL(agent_kernel, dim3(blocks), dim3(256), 0, stream,
                     own_raw, ally_raw, enemy_raw, hidden, bm,
                     d_ws, (float*)d_out, BN);
}